// Round 5
// baseline (348.582 us; speedup 1.0000x reference)
//
#include <hip/hip_runtime.h>

#define DEV __device__ __forceinline__

typedef _Float16 f16;
typedef __attribute__((ext_vector_type(8))) _Float16 f16x8;
typedef __attribute__((ext_vector_type(4))) _Float16 f16x4;
typedef __attribute__((ext_vector_type(2))) __fp16 fp16v2;
typedef __attribute__((ext_vector_type(4))) float floatx4;

constexpr int DMODEL = 1024;
constexpr int SLEN = 2048;
// 1/sqrt(64) * log2(e): softmax done in exp2 space (exact same result)
constexpr float SCALE_Q = 0.125f * 1.4426950408889634f;

// async global->LDS, 16B per lane. lds is wave-uniform base; HW scatters lane i to base + 16*i.
DEV void gll16(const void* g, void* lds) {
    __builtin_amdgcn_global_load_lds((const __attribute__((address_space(1))) void*)g,
                                     (__attribute__((address_space(3))) void*)lds, 16, 0, 0);
}

#if __has_builtin(__builtin_amdgcn_exp2f)
DEV float fast_exp2(float x) { return __builtin_amdgcn_exp2f(x); }
#else
DEV float fast_exp2(float x) { return __expf(x * 0.6931471805599453f); }
#endif

DEV unsigned pkh2(float a, float b) {
    union { fp16v2 h; unsigned u; } c;
    c.h = __builtin_amdgcn_cvt_pkrtz(a, b);   // lo=a, hi=b
    return c.u;
}

#if __has_builtin(__builtin_amdgcn_permlane32_swap) && __has_builtin(__builtin_amdgcn_permlane16_swap)
DEV void pl32swap(unsigned& x, unsigned& y) {
    auto r = __builtin_amdgcn_permlane32_swap(x, y, false, false);
    x = r[0]; y = r[1];
}
DEV void pl16swap(unsigned& x, unsigned& y) {
    auto r = __builtin_amdgcn_permlane16_swap(x, y, false, false);
    x = r[0]; y = r[1];
}
#else
DEV void pl32swap(unsigned& x, unsigned& y) {
    unsigned xs = (unsigned)__shfl_xor((int)x, 32, 64);
    unsigned ys = (unsigned)__shfl_xor((int)y, 32, 64);
    bool lo = (threadIdx.x & 63) < 32;
    unsigned nx = lo ? x : ys, ny = lo ? xs : y;
    x = nx; y = ny;
}
DEV void pl16swap(unsigned& x, unsigned& y) {
    unsigned xs = (unsigned)__shfl_xor((int)x, 16, 64);
    unsigned ys = (unsigned)__shfl_xor((int)y, 16, 64);
    bool ev = (((threadIdx.x & 63) >> 4) & 1) == 0;
    unsigned nx = ev ? x : ys, ny = ev ? xs : y;
    x = nx; y = ny;
}
#endif

// C-layout (St tiles 2c,2c+1) -> exp2 -> PV B-operand fragment for kv-chunk c.
DEV f16x8 xform(const floatx4& s0, const floatx4& s1) {
    unsigned X  = pkh2(fast_exp2(s0[0]), fast_exp2(s0[1]));
    unsigned Xp = pkh2(fast_exp2(s0[2]), fast_exp2(s0[3]));
    unsigned Y  = pkh2(fast_exp2(s1[0]), fast_exp2(s1[1]));
    unsigned Yp = pkh2(fast_exp2(s1[2]), fast_exp2(s1[3]));
    pl32swap(X, Y);  pl16swap(X, Y);    // X=b0, Y=b2
    pl32swap(Xp, Yp); pl16swap(Xp, Yp); // Xp=b1, Yp=b3
    union { unsigned u[4]; f16x8 v; } o;
    o.u[0] = X; o.u[1] = Xp; o.u[2] = Y; o.u[3] = Yp;
    return o.v;
}

// ---------------------------------------------------------------------------
// 3x fp32->fp16 bulk convert. grid = 3*4096, 256 thr, 8 elems/thread.
// ---------------------------------------------------------------------------
__global__ void cvt3(const float* __restrict__ A0, const float* __restrict__ A1,
                     const float* __restrict__ A2, f16* __restrict__ O0,
                     f16* __restrict__ O1, f16* __restrict__ O2) {
    const int seg = blockIdx.x >> 12;
    const int i = (blockIdx.x & 4095) * 256 + threadIdx.x;
    const float* in = seg == 0 ? A0 : seg == 1 ? A1 : A2;
    f16* out = seg == 0 ? O0 : seg == 1 ? O1 : O2;
    const float4 a = ((const float4*)in)[2 * i];
    const float4 b = ((const float4*)in)[2 * i + 1];
    f16x8 h;
    h[0] = (f16)a.x; h[1] = (f16)a.y; h[2] = (f16)a.z; h[3] = (f16)a.w;
    h[4] = (f16)b.x; h[5] = (f16)b.y; h[6] = (f16)b.z; h[7] = (f16)b.w;
    ((f16x8*)out)[i] = h;
}

// ---------------------------------------------------------------------------
// 4x weight transpose + convert:  Wt[n][k] = (f16)W[k][n].  grid 4096.
// ---------------------------------------------------------------------------
__global__ void wtrans4(const float* __restrict__ W0, const float* __restrict__ W1,
                        const float* __restrict__ W2, const float* __restrict__ W3,
                        f16* __restrict__ T0, f16* __restrict__ T1,
                        f16* __restrict__ T2, f16* __restrict__ T3) {
    __shared__ float t[32][33];
    const int w = blockIdx.x >> 10, bid = blockIdx.x & 1023;
    const float* W = w == 0 ? W0 : w == 1 ? W1 : w == 2 ? W2 : W3;
    f16* Wt = w == 0 ? T0 : w == 1 ? T1 : w == 2 ? T2 : T3;
    const int tn = bid & 31, tk = bid >> 5;
    const int c = threadIdx.x & 31, r0 = threadIdx.x >> 5;
    for (int i = 0; i < 4; ++i) {
        int r = r0 + i * 8;
        t[r][c] = W[(tk * 32 + r) * DMODEL + tn * 32 + c];
    }
    __syncthreads();
    for (int i = 0; i < 4; ++i) {
        int r = r0 + i * 8;
        Wt[(tn * 32 + r) * DMODEL + tk * 32 + c] = (f16)t[c][r];
    }
}

// ---------------------------------------------------------------------------
// QKV GEMM (fused or single): C = A @ Bt^T + bias, 128x128 tile, BK=32.
// seg = blockIdx.x>>9 picks operand set; epi = epi_base + seg:
//   0: Q -> f16 [bh][s][d_swz] scaled by SCALE_Q
//   1: K -> f16 [bh][s][d_swz]
//   2: V -> f16 [bh][d][s_swz-in-128-tile]
// ---------------------------------------------------------------------------
__global__ __launch_bounds__(256, 3)
void gemm_qkv(const f16* __restrict__ A0, const f16* __restrict__ A1, const f16* __restrict__ A2,
              const f16* __restrict__ B0, const f16* __restrict__ B1, const f16* __restrict__ B2,
              const float* __restrict__ bi0, const float* __restrict__ bi1, const float* __restrict__ bi2,
              f16* __restrict__ C0, f16* __restrict__ C1, f16* __restrict__ C2, int epi_base) {
    __shared__ f16 As[128 * 32];
    __shared__ f16 Bs[128 * 32];
    const int seg = blockIdx.x >> 9, inner = blockIdx.x & 511;
    const int epi = epi_base + seg;
    const f16* A = seg == 0 ? A0 : seg == 1 ? A1 : A2;
    const f16* Bt = seg == 0 ? B0 : seg == 1 ? B1 : B2;
    const float* bias = seg == 0 ? bi0 : seg == 1 ? bi1 : bi2;
    f16* Cp = seg == 0 ? C0 : seg == 1 ? C1 : C2;

    const int tid = threadIdx.x;
    const int wid = tid >> 6, lane = tid & 63;
    const int quad = lane >> 4, l16 = lane & 15;
    const int bm = inner & 63, bn = inner >> 6;
    const int row0 = bm * 128, col0 = bn * 128;
    const int wm = (wid >> 1) * 64, wn = (wid & 1) * 64;

    floatx4 acc[4][4];
    for (int i = 0; i < 4; ++i)
        for (int j = 0; j < 4; ++j) acc[i][j] = {0.f, 0.f, 0.f, 0.f};

    for (int k0 = 0; k0 < DMODEL; k0 += 32) {
        __syncthreads();
        for (int j = 0; j < 2; ++j) {
            int off = (j * 4 + wid) * 1024 + lane * 16;
            int r = off >> 6, cb = (off & 63) >> 1;
            gll16(Bt + (col0 + r) * DMODEL + k0 + cb, (char*)Bs + (j * 4 + wid) * 1024);
            gll16(A + (row0 + r) * DMODEL + k0 + cb, (char*)As + (j * 4 + wid) * 1024);
        }
        __syncthreads();

        f16x8 af[4], bf[4];
        for (int mi = 0; mi < 4; ++mi)
            af[mi] = *(const f16x8*)&As[(wm + mi * 16 + l16) * 32 + quad * 8];
        for (int ni = 0; ni < 4; ++ni)
            bf[ni] = *(const f16x8*)&Bs[(wn + ni * 16 + l16) * 32 + quad * 8];
        for (int mi = 0; mi < 4; ++mi)
            for (int ni = 0; ni < 4; ++ni)
                acc[mi][ni] = __builtin_amdgcn_mfma_f32_16x16x32_f16(af[mi], bf[ni], acc[mi][ni], 0, 0, 0);
    }

    const float scale = (epi == 0) ? SCALE_Q : 1.0f;
    for (int mi = 0; mi < 4; ++mi) {
        for (int ni = 0; ni < 4; ++ni) {
            const int gr0 = row0 + wm + mi * 16 + quad * 4;
            const int gc = col0 + wn + ni * 16 + l16;
            const float bv = bias[gc];
            if (epi == 2) {
                const int b_ = gr0 >> 11, s0 = gr0 & 2047;
                const int h_ = gc >> 6, d_ = gc & 63;
                const int bh = b_ * 16 + h_;
                const int csw = ((s0 >> 3) & 15) ^ (d_ & 7);
                const int s0w = (s0 & ~127) | (csw << 3) | (s0 & 7);
                f16x4 o;
                for (int r = 0; r < 4; ++r) o[r] = (f16)(acc[mi][ni][r] + bv);
                *(f16x4*)&Cp[(bh * 64 + d_) * SLEN + s0w] = o;
            } else {
                for (int r = 0; r < 4; ++r) {
                    const int gr = gr0 + r;
                    const int b_ = gr >> 11, s_ = gr & 2047;
                    const int h_ = gc >> 6, d_ = gc & 63;
                    const int bh = b_ * 16 + h_;
                    const int dsw = (((d_ >> 3) ^ (s_ & 7)) << 3) | (d_ & 7);
                    Cp[(bh * SLEN + s_) * 64 + dsw] = (f16)((acc[mi][ni][r] + bv) * scale);
                }
            }
        }
    }
}

// ---------------------------------------------------------------------------
// Output projection GEMM: out(fp32) = At(f16) @ Wo^T + bo.
// ---------------------------------------------------------------------------
__global__ __launch_bounds__(256, 3)
void gemm_out(const f16* __restrict__ A, const f16* __restrict__ Bt,
              const float* __restrict__ bias, float* __restrict__ Cp) {
    __shared__ f16 As[128 * 32];
    __shared__ f16 Bs[128 * 32];
    const int tid = threadIdx.x;
    const int wid = tid >> 6, lane = tid & 63;
    const int quad = lane >> 4, l16 = lane & 15;
    const int bm = blockIdx.x & 63, bn = blockIdx.x >> 6;
    const int row0 = bm * 128, col0 = bn * 128;
    const int wm = (wid >> 1) * 64, wn = (wid & 1) * 64;

    floatx4 acc[4][4];
    for (int i = 0; i < 4; ++i)
        for (int j = 0; j < 4; ++j) acc[i][j] = {0.f, 0.f, 0.f, 0.f};

    for (int k0 = 0; k0 < DMODEL; k0 += 32) {
        __syncthreads();
        for (int j = 0; j < 2; ++j) {
            int off = (j * 4 + wid) * 1024 + lane * 16;
            int r = off >> 6, cb = (off & 63) >> 1;
            gll16(Bt + (col0 + r) * DMODEL + k0 + cb, (char*)Bs + (j * 4 + wid) * 1024);
            gll16(A + (row0 + r) * DMODEL + k0 + cb, (char*)As + (j * 4 + wid) * 1024);
        }
        __syncthreads();

        f16x8 af[4], bf[4];
        for (int mi = 0; mi < 4; ++mi)
            af[mi] = *(const f16x8*)&As[(wm + mi * 16 + l16) * 32 + quad * 8];
        for (int ni = 0; ni < 4; ++ni)
            bf[ni] = *(const f16x8*)&Bs[(wn + ni * 16 + l16) * 32 + quad * 8];
        for (int mi = 0; mi < 4; ++mi)
            for (int ni = 0; ni < 4; ++ni)
                acc[mi][ni] = __builtin_amdgcn_mfma_f32_16x16x32_f16(af[mi], bf[ni], acc[mi][ni], 0, 0, 0);
    }

    for (int mi = 0; mi < 4; ++mi)
        for (int ni = 0; ni < 4; ++ni) {
            const int gr0 = row0 + wm + mi * 16 + quad * 4;
            const int gc = col0 + wn + ni * 16 + l16;
            const float bv = bias[gc];
            for (int r = 0; r < 4; ++r)
                Cp[(gr0 + r) * DMODEL + gc] = acc[mi][ni][r] + bv;
        }
}

// ---------------------------------------------------------------------------
// Flash attention, transposed formulation. Block = 128 q-rows, 4 waves x 32 q.
// St = K·Q^T (C-layout) -> register permlane transform -> PV B-operand;
// O^T = V^T·P with ones-A-tile (md=4) accumulating softmax denominator.
// Rotated chunk pipeline: QK(c) -> PV(c-1) -> xform(c); PV MFMAs hide the
// QK->exp dependency latency. XCD swizzle: each XCD owns 8 bh (4MB K/V = L2).
// LDS 32KB -> 4 blocks/CU = 4 waves/SIMD.
// ---------------------------------------------------------------------------
__global__ __launch_bounds__(256, 4)
void flash_k(const f16* __restrict__ Qh, const f16* __restrict__ Kh,
             const f16* __restrict__ Vt, f16* __restrict__ attn) {
    __shared__ f16 smem[16384];          // 32 KB
    f16* Qs = smem;                      // [128][64] swz (start only)
    f16* Ks = smem;                      // [128][64] swz
    f16* Vs = smem + 8192;               // [64][128] swz

    const int tid = threadIdx.x;
    const int wid = tid >> 6, lane = tid & 63;
    const int quad = lane >> 4, l16 = lane & 15;
    // XCD swizzle: blocks of one XCD (stride-8 round robin) share 8 bh values
    const int xcd = blockIdx.x & 7, jj = blockIdx.x >> 3;
    const int bh = xcd * 8 + (jj & 7), qt = jj >> 3;
    const int mq = wid * 32;

    const f16* Qbase = Qh + (bh * SLEN + qt * 128) * 64;
#pragma unroll
    for (int j = 0; j < 4; ++j) {
        const int ch = j * 4 + wid;
        gll16(Qbase + ch * 512 + lane * 8, (char*)Qs + ch * 1024);
    }
    __syncthreads();

    f16x8 qf[2][2];
#pragma unroll
    for (int nq = 0; nq < 2; ++nq)
#pragma unroll
        for (int kc = 0; kc < 2; ++kc)
            qf[nq][kc] = *(const f16x8*)&Qs[(mq + nq * 16 + l16) * 64 +
                                            (((kc * 4 + quad) ^ (l16 & 7)) << 3)];

    floatx4 oacc[2][5];                  // [nq][md]; md=4 = row-sum (ones tile)
    for (int nq = 0; nq < 2; ++nq)
        for (int md = 0; md < 5; ++md) oacc[nq][md] = {0.f, 0.f, 0.f, 0.f};

    const f16x8 ones = {(f16)1, (f16)1, (f16)1, (f16)1, (f16)1, (f16)1, (f16)1, (f16)1};
    const f16* Kb = Kh + bh * SLEN * 64;
    const f16* Vb = Vt + bh * 64 * SLEN;

    for (int kv0 = 0; kv0 < SLEN; kv0 += 128) {
        __syncthreads();  // prior tile's reads (and initial qf reads) done
#pragma unroll
        for (int j = 0; j < 4; ++j) {
            const int ch = j * 4 + wid;
            gll16(Kb + kv0 * 64 + ch * 512 + lane * 8, (char*)Ks + ch * 1024);
        }
#pragma unroll
        for (int j = 0; j < 4; ++j) {
            const int ch = j * 4 + wid;
            const int ci = ch * 64 + lane;
            const int d_ = ci >> 4, o_ = (ci & 15) * 8;
            gll16(Vb + d_ * SLEN + kv0 + o_, (char*)Vs + ch * 1024);
        }
        __syncthreads();  // staging visible

        f16x8 pf[2];
#pragma unroll
        for (int c = 0; c < 4; ++c) {   // kv chunk of 32
            floatx4 sacc[2][2];
            for (int nq = 0; nq < 2; ++nq)
                for (int t = 0; t < 2; ++t) sacc[nq][t] = {0.f, 0.f, 0.f, 0.f};
#pragma unroll
            for (int t = 0; t < 2; ++t) {
                const int a = c * 2 + t;    // 16-row kv tile
#pragma unroll
                for (int kc = 0; kc < 2; ++kc) {
                    f16x8 kf = *(const f16x8*)&Ks[(a * 16 + l16) * 64 +
                                                  (((kc * 4 + quad) ^ (l16 & 7)) << 3)];
                    for (int nq = 0; nq < 2; ++nq)
                        sacc[nq][t] = __builtin_amdgcn_mfma_f32_16x16x32_f16(
                            kf, qf[nq][kc], sacc[nq][t], 0, 0, 0);
                }
            }
            if (c > 0) {  // PV for previous chunk — hides QK->exp latency
                const int cp = c - 1;
#pragma unroll
                for (int md = 0; md < 4; ++md) {
                    f16x8 vf = *(const f16x8*)&Vs[(md * 16 + l16) * 128 +
                                                  (((cp * 4 + quad) ^ (l16 & 7)) << 3)];
                    for (int nq = 0; nq < 2; ++nq)
                        oacc[nq][md] = __builtin_amdgcn_mfma_f32_16x16x32_f16(
                            vf, pf[nq], oacc[nq][md], 0, 0, 0);
                }
                for (int nq = 0; nq < 2; ++nq)
                    oacc[nq][4] = __builtin_amdgcn_mfma_f32_16x16x32_f16(
                        ones, pf[nq], oacc[nq][4], 0, 0, 0);
            }
#pragma unroll
            for (int nq = 0; nq < 2; ++nq) pf[nq] = xform(sacc[nq][0], sacc[nq][1]);
        }
        // PV for last chunk (c=3) of this tile
#pragma unroll
        for (int md = 0; md < 4; ++md) {
            f16x8 vf = *(const f16x8*)&Vs[(md * 16 + l16) * 128 +
                                          (((3 * 4 + quad) ^ (l16 & 7)) << 3)];
            for (int nq = 0; nq < 2; ++nq)
                oacc[nq][md] = __builtin_amdgcn_mfma_f32_16x16x32_f16(
                    vf, pf[nq], oacc[nq][md], 0, 0, 0);
        }
        for (int nq = 0; nq < 2; ++nq)
            oacc[nq][4] = __builtin_amdgcn_mfma_f32_16x16x32_f16(
                ones, pf[nq], oacc[nq][4], 0, 0, 0);
    }

    // epilogue: lane holds O^T[d = md*16+quad*4+r][q = mq+nq*16+l16] and its own
    // row-sum in oacc[nq][4] (all regs equal) -> normalize, no shuffles.
    const int b_ = bh >> 4, h_ = bh & 15;
#pragma unroll
    for (int nq = 0; nq < 2; ++nq) {
        const float linv = __frcp_rn(oacc[nq][4][0]);
        const int tok = b_ * SLEN + qt * 128 + mq + nq * 16 + l16;
#pragma unroll
        for (int md = 0; md < 4; ++md) {
            f16x4 o;
            for (int r = 0; r < 4; ++r) o[r] = (f16)(oacc[nq][md][r] * linv);
            *(f16x4*)&attn[tok * DMODEL + h_ * 64 + md * 16 + quad * 4] = o;
        }
    }
}

// ---------------------------------------------------------------------------
extern "C" void kernel_launch(void* const* d_in, const int* in_sizes, int n_in,
                              void* d_out, int out_size, void* d_ws, size_t ws_size,
                              hipStream_t stream) {
    (void)in_sizes; (void)n_in; (void)out_size;
    const float* Q_in = (const float*)d_in[0];
    const float* K_in = (const float*)d_in[1];
    const float* V_in = (const float*)d_in[2];
    const float* Wq = (const float*)d_in[3];
    const float* bq = (const float*)d_in[4];
    const float* Wk = (const float*)d_in[5];
    const float* bk = (const float*)d_in[6];
    const float* Wv = (const float*)d_in[7];
    const float* bv = (const float*)d_in[8];
    const float* Wo = (const float*)d_in[9];
    const float* bo = (const float*)d_in[10];
    float* out = (float*)d_out;

    char* ws = (char*)d_ws;
    const size_t MB = 1u << 20;
    f16* wtq = (f16*)(ws + 0 * MB);
    f16* wtk = (f16*)(ws + 2 * MB);
    f16* wtv = (f16*)(ws + 4 * MB);
    f16* wto = (f16*)(ws + 6 * MB);
    f16* Qh  = (f16*)(ws + 8 * MB);
    f16* Kh  = (f16*)(ws + 24 * MB);
    f16* Vt  = (f16*)(ws + 40 * MB);
    f16* At  = (f16*)(ws + 56 * MB);

    wtrans4<<<4096, 256, 0, stream>>>(Wq, Wk, Wv, Wo, wtq, wtk, wtv, wto);

    if (ws_size >= 120 * MB) {
        // fused path: 3 convert buffers + one 1536-block QKV GEMM launch
        f16* Ac0 = (f16*)(ws + 72 * MB);
        f16* Ac1 = (f16*)(ws + 88 * MB);
        f16* Ac2 = (f16*)(ws + 104 * MB);
        cvt3<<<3 * 4096, 256, 0, stream>>>(Q_in, K_in, V_in, Ac0, Ac1, Ac2);
        gemm_qkv<<<1536, 256, 0, stream>>>(Ac0, Ac1, Ac2, wtq, wtk, wtv,
                                           bq, bk, bv, Qh, Kh, Vt, 0);
    } else {
        // sequential fallback: single convert buffer aliasing At
        f16* Ac = At;
        cvt3<<<4096, 256, 0, stream>>>(Q_in, Q_in, Q_in, Ac, Ac, Ac);
        gemm_qkv<<<512, 256, 0, stream>>>(Ac, Ac, Ac, wtq, wtq, wtq, bq, bq, bq,
                                          Qh, Qh, Qh, 0);
        cvt3<<<4096, 256, 0, stream>>>(K_in, K_in, K_in, Ac, Ac, Ac);
        gemm_qkv<<<512, 256, 0, stream>>>(Ac, Ac, Ac, wtk, wtk, wtk, bk, bk, bk,
                                          Kh, Kh, Kh, 1);
        cvt3<<<4096, 256, 0, stream>>>(V_in, V_in, V_in, Ac, Ac, Ac);
        gemm_qkv<<<512, 256, 0, stream>>>(Ac, Ac, Ac, wtv, wtv, wtv, bv, bv, bv,
                                          Vt, Vt, Vt, 2);
    }

    flash_k<<<1024, 256, 0, stream>>>(Qh, Kh, Vt, At);
    gemm_out<<<512, 256, 0, stream>>>(At, wto, bo, out);
}

// Round 6
// 323.667 us; speedup vs baseline: 1.0770x; 1.0770x over previous
//
#include <hip/hip_runtime.h>

#define DEV __device__ __forceinline__

typedef _Float16 f16;
typedef __attribute__((ext_vector_type(8))) _Float16 f16x8;
typedef __attribute__((ext_vector_type(4))) _Float16 f16x4;
typedef __attribute__((ext_vector_type(2))) __fp16 fp16v2;
typedef __attribute__((ext_vector_type(4))) float floatx4;

constexpr int DMODEL = 1024;
constexpr int SLEN = 2048;
// 1/sqrt(64) * log2(e): softmax done in exp2 space (exact same result)
constexpr float SCALE_Q = 0.125f * 1.4426950408889634f;

// async global->LDS, 16B per lane. lds is wave-uniform base; HW scatters lane i to base + 16*i.
DEV void gll16(const void* g, void* lds) {
    __builtin_amdgcn_global_load_lds((const __attribute__((address_space(1))) void*)g,
                                     (__attribute__((address_space(3))) void*)lds, 16, 0, 0);
}

#if __has_builtin(__builtin_amdgcn_exp2f)
DEV float fast_exp2(float x) { return __builtin_amdgcn_exp2f(x); }
#else
DEV float fast_exp2(float x) { return __expf(x * 0.6931471805599453f); }
#endif

DEV unsigned pkh2(float a, float b) {
    union { fp16v2 h; unsigned u; } c;
    c.h = __builtin_amdgcn_cvt_pkrtz(a, b);   // lo=a, hi=b
    return c.u;
}

#if __has_builtin(__builtin_amdgcn_permlane32_swap) && __has_builtin(__builtin_amdgcn_permlane16_swap)
DEV void pl32swap(unsigned& x, unsigned& y) {
    auto r = __builtin_amdgcn_permlane32_swap(x, y, false, false);
    x = r[0]; y = r[1];
}
DEV void pl16swap(unsigned& x, unsigned& y) {
    auto r = __builtin_amdgcn_permlane16_swap(x, y, false, false);
    x = r[0]; y = r[1];
}
#else
DEV void pl32swap(unsigned& x, unsigned& y) {
    unsigned xs = (unsigned)__shfl_xor((int)x, 32, 64);
    unsigned ys = (unsigned)__shfl_xor((int)y, 32, 64);
    bool lo = (threadIdx.x & 63) < 32;
    unsigned nx = lo ? x : ys, ny = lo ? xs : y;
    x = nx; y = ny;
}
DEV void pl16swap(unsigned& x, unsigned& y) {
    unsigned xs = (unsigned)__shfl_xor((int)x, 16, 64);
    unsigned ys = (unsigned)__shfl_xor((int)y, 16, 64);
    bool ev = (((threadIdx.x & 63) >> 4) & 1) == 0;
    unsigned nx = ev ? x : ys, ny = ev ? xs : y;
    x = nx; y = ny;
}
#endif

// C-layout (St tiles 2c,2c+1) -> exp2 -> PV B-operand fragment for kv-chunk c.
DEV f16x8 xform(const floatx4& s0, const floatx4& s1) {
    unsigned X  = pkh2(fast_exp2(s0[0]), fast_exp2(s0[1]));
    unsigned Xp = pkh2(fast_exp2(s0[2]), fast_exp2(s0[3]));
    unsigned Y  = pkh2(fast_exp2(s1[0]), fast_exp2(s1[1]));
    unsigned Yp = pkh2(fast_exp2(s1[2]), fast_exp2(s1[3]));
    pl32swap(X, Y);  pl16swap(X, Y);    // X=b0, Y=b2
    pl32swap(Xp, Yp); pl16swap(Xp, Yp); // Xp=b1, Yp=b3
    union { unsigned u[4]; f16x8 v; } o;
    o.u[0] = X; o.u[1] = Xp; o.u[2] = Y; o.u[3] = Yp;
    return o.v;
}

// ---------------------------------------------------------------------------
// 3x fp32->fp16 bulk convert. grid = 3*4096, 256 thr, 8 elems/thread.
// ---------------------------------------------------------------------------
__global__ void cvt3(const float* __restrict__ A0, const float* __restrict__ A1,
                     const float* __restrict__ A2, f16* __restrict__ O0,
                     f16* __restrict__ O1, f16* __restrict__ O2) {
    const int seg = blockIdx.x >> 12;
    const int i = (blockIdx.x & 4095) * 256 + threadIdx.x;
    const float* in = seg == 0 ? A0 : seg == 1 ? A1 : A2;
    f16* out = seg == 0 ? O0 : seg == 1 ? O1 : O2;
    const float4 a = ((const float4*)in)[2 * i];
    const float4 b = ((const float4*)in)[2 * i + 1];
    f16x8 h;
    h[0] = (f16)a.x; h[1] = (f16)a.y; h[2] = (f16)a.z; h[3] = (f16)a.w;
    h[4] = (f16)b.x; h[5] = (f16)b.y; h[6] = (f16)b.z; h[7] = (f16)b.w;
    ((f16x8*)out)[i] = h;
}

// ---------------------------------------------------------------------------
// 4x weight transpose + convert:  Wt[n][k] = (f16)W[k][n].  grid 4096.
// ---------------------------------------------------------------------------
__global__ void wtrans4(const float* __restrict__ W0, const float* __restrict__ W1,
                        const float* __restrict__ W2, const float* __restrict__ W3,
                        f16* __restrict__ T0, f16* __restrict__ T1,
                        f16* __restrict__ T2, f16* __restrict__ T3) {
    __shared__ float t[32][33];
    const int w = blockIdx.x >> 10, bid = blockIdx.x & 1023;
    const float* W = w == 0 ? W0 : w == 1 ? W1 : w == 2 ? W2 : W3;
    f16* Wt = w == 0 ? T0 : w == 1 ? T1 : w == 2 ? T2 : T3;
    const int tn = bid & 31, tk = bid >> 5;
    const int c = threadIdx.x & 31, r0 = threadIdx.x >> 5;
    for (int i = 0; i < 4; ++i) {
        int r = r0 + i * 8;
        t[r][c] = W[(tk * 32 + r) * DMODEL + tn * 32 + c];
    }
    __syncthreads();
    for (int i = 0; i < 4; ++i) {
        int r = r0 + i * 8;
        Wt[(tn * 32 + r) * DMODEL + tk * 32 + c] = (f16)t[c][r];
    }
}

// ---------------------------------------------------------------------------
// GEMM core: 128x128 tile, BK=32, double-buffered LDS with fine-grained
// vmcnt + raw s_barrier pipeline (stage(t+1) stays in flight across barriers;
// per-wave vmcnt(4)+barrier => all waves' stage(t) complete, no full drain).
// ---------------------------------------------------------------------------
DEV void gemm_core(const f16* __restrict__ A, const f16* __restrict__ Bt,
                   f16* smem, int row0, int col0, int tid, floatx4 (&acc)[4][4]) {
    const int wid = tid >> 6, lane = tid & 63;
    const int quad = lane >> 4, l16 = lane & 15;
    const int wm = (wid >> 1) * 64, wn = (wid & 1) * 64;
    const int off = wid * 1024 + lane * 16;   // byte offset of this wave's chunk 0
    const int r = off >> 6, cb = (off & 63) >> 1;

    // stage k-iter 0 into buf0
    {
        gll16(Bt + (col0 + r) * DMODEL + cb, (char*)(smem + 4096) + wid * 1024);
        gll16(Bt + (col0 + r + 64) * DMODEL + cb, (char*)(smem + 4096) + 4096 + wid * 1024);
        gll16(A + (row0 + r) * DMODEL + cb, (char*)smem + wid * 1024);
        gll16(A + (row0 + r + 64) * DMODEL + cb, (char*)smem + 4096 + wid * 1024);
    }
    for (int it = 0; it < 32; ++it) {
        f16* As = smem + (it & 1) * 8192;
        f16* Bs = As + 4096;
        if (it < 31) {
            const int k0 = (it + 1) * 32;
            f16* An = smem + ((it + 1) & 1) * 8192;
            f16* Bn = An + 4096;
            gll16(Bt + (col0 + r) * DMODEL + k0 + cb, (char*)Bn + wid * 1024);
            gll16(Bt + (col0 + r + 64) * DMODEL + k0 + cb, (char*)Bn + 4096 + wid * 1024);
            gll16(A + (row0 + r) * DMODEL + k0 + cb, (char*)An + wid * 1024);
            gll16(A + (row0 + r + 64) * DMODEL + k0 + cb, (char*)An + 4096 + wid * 1024);
            __builtin_amdgcn_s_waitcnt(0xF74);   // vmcnt(4): own stage(it) done
        } else {
            __builtin_amdgcn_s_waitcnt(0xF70);   // vmcnt(0)
        }
        __builtin_amdgcn_s_barrier();            // all waves' stage(it) done

        f16x8 af[4], bf[4];
        for (int mi = 0; mi < 4; ++mi)
            af[mi] = *(const f16x8*)&As[(wm + mi * 16 + l16) * 32 + quad * 8];
        for (int ni = 0; ni < 4; ++ni)
            bf[ni] = *(const f16x8*)&Bs[(wn + ni * 16 + l16) * 32 + quad * 8];
        for (int mi = 0; mi < 4; ++mi)
            for (int ni = 0; ni < 4; ++ni)
                acc[mi][ni] = __builtin_amdgcn_mfma_f32_16x16x32_f16(af[mi], bf[ni], acc[mi][ni], 0, 0, 0);
        __builtin_amdgcn_s_barrier();            // buf[it&1] free for stage(it+2)
    }
}

// ---------------------------------------------------------------------------
// QKV GEMM (fused or single): seg = blockIdx.x>>9; epi = epi_base + seg:
//   0: Q -> f16 [bh][s][d_swz] scaled by SCALE_Q
//   1: K -> f16 [bh][s][d_swz]
//   2: V -> f16 [bh][d][s_swz-in-128-tile]
// ---------------------------------------------------------------------------
__global__ __launch_bounds__(256, 3)
void gemm_qkv(const f16* __restrict__ A0, const f16* __restrict__ A1, const f16* __restrict__ A2,
              const f16* __restrict__ B0, const f16* __restrict__ B1, const f16* __restrict__ B2,
              const float* __restrict__ bi0, const float* __restrict__ bi1, const float* __restrict__ bi2,
              f16* __restrict__ C0, f16* __restrict__ C1, f16* __restrict__ C2, int epi_base) {
    __shared__ f16 smem[16384];   // 32 KB: 2 x (As 8KB + Bs 8KB)
    const int seg = blockIdx.x >> 9, inner = blockIdx.x & 511;
    const int epi = epi_base + seg;
    const f16* A = seg == 0 ? A0 : seg == 1 ? A1 : A2;
    const f16* Bt = seg == 0 ? B0 : seg == 1 ? B1 : B2;
    const float* bias = seg == 0 ? bi0 : seg == 1 ? bi1 : bi2;
    f16* Cp = seg == 0 ? C0 : seg == 1 ? C1 : C2;

    const int tid = threadIdx.x;
    const int wid = tid >> 6, lane = tid & 63;
    const int quad = lane >> 4, l16 = lane & 15;
    const int bm = inner & 63, bn = inner >> 6;
    const int row0 = bm * 128, col0 = bn * 128;
    const int wm = (wid >> 1) * 64, wn = (wid & 1) * 64;

    floatx4 acc[4][4];
    for (int i = 0; i < 4; ++i)
        for (int j = 0; j < 4; ++j) acc[i][j] = {0.f, 0.f, 0.f, 0.f};

    gemm_core(A, Bt, smem, row0, col0, tid, acc);

    const float scale = (epi == 0) ? SCALE_Q : 1.0f;
    for (int mi = 0; mi < 4; ++mi) {
        for (int ni = 0; ni < 4; ++ni) {
            const int gr0 = row0 + wm + mi * 16 + quad * 4;
            const int gc = col0 + wn + ni * 16 + l16;
            const float bv = bias[gc];
            if (epi == 2) {
                const int b_ = gr0 >> 11, s0 = gr0 & 2047;
                const int h_ = gc >> 6, d_ = gc & 63;
                const int bh = b_ * 16 + h_;
                const int csw = ((s0 >> 3) & 15) ^ (d_ & 7);
                const int s0w = (s0 & ~127) | (csw << 3) | (s0 & 7);
                f16x4 o;
                for (int r = 0; r < 4; ++r) o[r] = (f16)(acc[mi][ni][r] + bv);
                *(f16x4*)&Cp[(bh * 64 + d_) * SLEN + s0w] = o;
            } else {
                for (int r = 0; r < 4; ++r) {
                    const int gr = gr0 + r;
                    const int b_ = gr >> 11, s_ = gr & 2047;
                    const int h_ = gc >> 6, d_ = gc & 63;
                    const int bh = b_ * 16 + h_;
                    const int dsw = (((d_ >> 3) ^ (s_ & 7)) << 3) | (d_ & 7);
                    Cp[(bh * SLEN + s_) * 64 + dsw] = (f16)((acc[mi][ni][r] + bv) * scale);
                }
            }
        }
    }
}

// ---------------------------------------------------------------------------
// Output projection GEMM: out(fp32) = At(f16) @ Wo^T + bo.
// ---------------------------------------------------------------------------
__global__ __launch_bounds__(256, 3)
void gemm_out(const f16* __restrict__ A, const f16* __restrict__ Bt,
              const float* __restrict__ bias, float* __restrict__ Cp) {
    __shared__ f16 smem[16384];
    const int tid = threadIdx.x;
    const int wid = tid >> 6, lane = tid & 63;
    const int quad = lane >> 4, l16 = lane & 15;
    const int bm = blockIdx.x & 63, bn = blockIdx.x >> 6;
    const int row0 = bm * 128, col0 = bn * 128;
    const int wm = (wid >> 1) * 64, wn = (wid & 1) * 64;

    floatx4 acc[4][4];
    for (int i = 0; i < 4; ++i)
        for (int j = 0; j < 4; ++j) acc[i][j] = {0.f, 0.f, 0.f, 0.f};

    gemm_core(A, Bt, smem, row0, col0, tid, acc);

    for (int mi = 0; mi < 4; ++mi)
        for (int ni = 0; ni < 4; ++ni) {
            const int gr0 = row0 + wm + mi * 16 + quad * 4;
            const int gc = col0 + wn + ni * 16 + l16;
            const float bv = bias[gc];
            for (int r = 0; r < 4; ++r)
                Cp[(gr0 + r) * DMODEL + gc] = acc[mi][ni][r] + bv;
        }
}

// ---------------------------------------------------------------------------
// Flash attention v3. Block = 256 q-rows, 4 waves x 64 q (nq=4). Grid 512.
// St = K·Q^T -> register permlane xform -> PV B-operand; O^T = V^T·P with
// ones-A-tile row-sum. K/V double-buffered in 64KB LDS; fine vmcnt(8) + raw
// barriers keep next tile's loads in flight across the barrier (no drain).
// XCD swizzle: each XCD owns 8 bh -> 4.2MB K/V working set ~ L2.
// ---------------------------------------------------------------------------
__global__ __launch_bounds__(256, 2)
void flash_k(const f16* __restrict__ Qh, const f16* __restrict__ Kh,
             const f16* __restrict__ Vt, f16* __restrict__ attn) {
    __shared__ f16 smem[32768];          // 64 KB: buf b at b*16384 (Ks 8K f16 + Vs 8K f16)
    const int tid = threadIdx.x;
    const int wid = tid >> 6, lane = tid & 63;
    const int quad = lane >> 4, l16 = lane & 15;
    const int xcd = blockIdx.x & 7, jj = blockIdx.x >> 3;
    const int bh = xcd * 8 + (jj & 7), qt = jj >> 3;   // qt 0..7, 256 q-rows each
    const int wq = wid * 64;

    // stage Q tile (256x64 = 32KB) into buf1 region, read fragments
    f16* Qs = smem + 16384;
    const f16* Qbase = Qh + (bh * SLEN + qt * 256) * 64;
#pragma unroll
    for (int j = 0; j < 8; ++j) {
        const int ch = j * 4 + wid;
        gll16(Qbase + ch * 512 + lane * 8, (char*)Qs + ch * 1024);
    }
    __syncthreads();

    f16x8 qf[4][2];
#pragma unroll
    for (int nq = 0; nq < 4; ++nq)
#pragma unroll
        for (int kc = 0; kc < 2; ++kc)
            qf[nq][kc] = *(const f16x8*)&Qs[(wq + nq * 16 + l16) * 64 +
                                            (((kc * 4 + quad) ^ (l16 & 7)) << 3)];
    __syncthreads();   // all qf reads done before buf1 is overwritten by stage(1)

    floatx4 oacc[4][5];                  // [nq][md]; md=4 = row-sum (ones tile)
    for (int nq = 0; nq < 4; ++nq)
        for (int md = 0; md < 5; ++md) oacc[nq][md] = {0.f, 0.f, 0.f, 0.f};

    const f16x8 ones = {(f16)1, (f16)1, (f16)1, (f16)1, (f16)1, (f16)1, (f16)1, (f16)1};
    const f16* Kb = Kh + bh * SLEN * 64;
    const f16* Vb = Vt + bh * 64 * SLEN;

    // stage tile 0 into buf0 (per wave: 4 K-chunks + 4 V-chunks)
#pragma unroll
    for (int j = 0; j < 4; ++j) {
        const int ch = j * 4 + wid;
        gll16(Kb + ch * 512 + lane * 8, (char*)smem + ch * 1024);
        const int ci = ch * 64 + lane;
        gll16(Vb + (ci >> 4) * SLEN + (ci & 15) * 8, (char*)(smem + 8192) + ch * 1024);
    }

    for (int t = 0; t < 16; ++t) {
        f16* Ks = smem + (t & 1) * 16384;
        f16* Vs = Ks + 8192;
        if (t < 15) {
            const int kv0n = (t + 1) * 128;
            f16* Kn = smem + ((t + 1) & 1) * 16384;
            f16* Vn = Kn + 8192;
#pragma unroll
            for (int j = 0; j < 4; ++j) {
                const int ch = j * 4 + wid;
                gll16(Kb + kv0n * 64 + ch * 512 + lane * 8, (char*)Kn + ch * 1024);
                const int ci = ch * 64 + lane;
                gll16(Vb + (ci >> 4) * SLEN + kv0n + (ci & 15) * 8, (char*)Vn + ch * 1024);
            }
            __builtin_amdgcn_s_waitcnt(0xF78);   // vmcnt(8): own stage(t) done
        } else {
            __builtin_amdgcn_s_waitcnt(0xF70);   // vmcnt(0)
        }
        __builtin_amdgcn_s_barrier();            // all waves' stage(t) done

        f16x8 pf[4];
#pragma unroll
        for (int c = 0; c < 4; ++c) {   // kv chunk of 32
            floatx4 sacc[4][2];
            for (int nq = 0; nq < 4; ++nq)
                for (int t2 = 0; t2 < 2; ++t2) sacc[nq][t2] = {0.f, 0.f, 0.f, 0.f};
#pragma unroll
            for (int t2 = 0; t2 < 2; ++t2) {
                const int a = c * 2 + t2;    // 16-row kv tile
#pragma unroll
                for (int kc = 0; kc < 2; ++kc) {
                    f16x8 kf = *(const f16x8*)&Ks[(a * 16 + l16) * 64 +
                                                  (((kc * 4 + quad) ^ (l16 & 7)) << 3)];
                    for (int nq = 0; nq < 4; ++nq)
                        sacc[nq][t2] = __builtin_amdgcn_mfma_f32_16x16x32_f16(
                            kf, qf[nq][kc], sacc[nq][t2], 0, 0, 0);
                }
            }
            if (c > 0) {  // PV for previous chunk — hides QK->exp latency
                const int cp = c - 1;
#pragma unroll
                for (int md = 0; md < 4; ++md) {
                    f16x8 vf = *(const f16x8*)&Vs[(md * 16 + l16) * 128 +
                                                  (((cp * 4 + quad) ^ (l16 & 7)) << 3)];
                    for (int nq = 0; nq < 4; ++nq)
                        oacc[nq][md] = __builtin_amdgcn_mfma_f32_16x16x32_f16(
                            vf, pf[nq], oacc[nq][md], 0, 0, 0);
                }
                for (int nq = 0; nq < 4; ++nq)
                    oacc[nq][4] = __builtin_amdgcn_mfma_f32_16x16x32_f16(
                        ones, pf[nq], oacc[nq][4], 0, 0, 0);
            }
#pragma unroll
            for (int nq = 0; nq < 4; ++nq) pf[nq] = xform(sacc[nq][0], sacc[nq][1]);
        }
        // PV for last chunk (c=3) of this tile
#pragma unroll
        for (int md = 0; md < 4; ++md) {
            f16x8 vf = *(const f16x8*)&Vs[(md * 16 + l16) * 128 +
                                          (((3 * 4 + quad) ^ (l16 & 7)) << 3)];
            for (int nq = 0; nq < 4; ++nq)
                oacc[nq][md] = __builtin_amdgcn_mfma_f32_16x16x32_f16(
                    vf, pf[nq], oacc[nq][md], 0, 0, 0);
        }
        for (int nq = 0; nq < 4; ++nq)
            oacc[nq][4] = __builtin_amdgcn_mfma_f32_16x16x32_f16(
                ones, pf[nq], oacc[nq][4], 0, 0, 0);

        __builtin_amdgcn_s_barrier();            // buf[t&1] free for stage(t+2)
    }

    // epilogue: lane holds O^T[d][q] and its own row-sum (oacc[nq][4], all regs equal)
    const int b_ = bh >> 4, h_ = bh & 15;
#pragma unroll
    for (int nq = 0; nq < 4; ++nq) {
        const float linv = __frcp_rn(oacc[nq][4][0]);
        const int tok = b_ * SLEN + qt * 256 + wq + nq * 16 + l16;
#pragma unroll
        for (int md = 0; md < 4; ++md) {
            f16x4 o;
            for (int r = 0; r < 4; ++r) o[r] = (f16)(oacc[nq][md][r] * linv);
            *(f16x4*)&attn[tok * DMODEL + h_ * 64 + md * 16 + quad * 4] = o;
        }
    }
}

// ---------------------------------------------------------------------------
extern "C" void kernel_launch(void* const* d_in, const int* in_sizes, int n_in,
                              void* d_out, int out_size, void* d_ws, size_t ws_size,
                              hipStream_t stream) {
    (void)in_sizes; (void)n_in; (void)out_size;
    const float* Q_in = (const float*)d_in[0];
    const float* K_in = (const float*)d_in[1];
    const float* V_in = (const float*)d_in[2];
    const float* Wq = (const float*)d_in[3];
    const float* bq = (const float*)d_in[4];
    const float* Wk = (const float*)d_in[5];
    const float* bk = (const float*)d_in[6];
    const float* Wv = (const float*)d_in[7];
    const float* bv = (const float*)d_in[8];
    const float* Wo = (const float*)d_in[9];
    const float* bo = (const float*)d_in[10];
    float* out = (float*)d_out;

    char* ws = (char*)d_ws;
    const size_t MB = 1u << 20;
    f16* wtq = (f16*)(ws + 0 * MB);
    f16* wtk = (f16*)(ws + 2 * MB);
    f16* wtv = (f16*)(ws + 4 * MB);
    f16* wto = (f16*)(ws + 6 * MB);
    f16* Qh  = (f16*)(ws + 8 * MB);
    f16* Kh  = (f16*)(ws + 24 * MB);
    f16* Vt  = (f16*)(ws + 40 * MB);
    f16* At  = (f16*)(ws + 56 * MB);

    wtrans4<<<4096, 256, 0, stream>>>(Wq, Wk, Wv, Wo, wtq, wtk, wtv, wto);

    if (ws_size >= 120 * MB) {
        // fused path: 3 convert buffers + one 1536-block QKV GEMM launch
        f16* Ac0 = (f16*)(ws + 72 * MB);
        f16* Ac1 = (f16*)(ws + 88 * MB);
        f16* Ac2 = (f16*)(ws + 104 * MB);
        cvt3<<<3 * 4096, 256, 0, stream>>>(Q_in, K_in, V_in, Ac0, Ac1, Ac2);
        gemm_qkv<<<1536, 256, 0, stream>>>(Ac0, Ac1, Ac2, wtq, wtk, wtv,
                                           bq, bk, bv, Qh, Kh, Vt, 0);
    } else {
        // sequential fallback: single convert buffer aliasing At
        f16* Ac = At;
        cvt3<<<4096, 256, 0, stream>>>(Q_in, Q_in, Q_in, Ac, Ac, Ac);
        gemm_qkv<<<512, 256, 0, stream>>>(Ac, Ac, Ac, wtq, wtq, wtq, bq, bq, bq,
                                          Qh, Qh, Qh, 0);
        cvt3<<<4096, 256, 0, stream>>>(K_in, K_in, K_in, Ac, Ac, Ac);
        gemm_qkv<<<512, 256, 0, stream>>>(Ac, Ac, Ac, wtk, wtk, wtk, bk, bk, bk,
                                          Kh, Kh, Kh, 1);
        cvt3<<<4096, 256, 0, stream>>>(V_in, V_in, V_in, Ac, Ac, Ac);
        gemm_qkv<<<512, 256, 0, stream>>>(Ac, Ac, Ac, wtv, wtv, wtv, bv, bv, bv,
                                          Vt, Vt, Vt, 2);
    }

    flash_k<<<512, 256, 0, stream>>>(Qh, Kh, Vt, At);
    gemm_out<<<512, 256, 0, stream>>>(At, wto, bo, out);
}